// Round 7
// baseline (156.243 us; speedup 1.0000x reference)
//
#include <hip/hip_runtime.h>

#define AREA 4096

typedef short short8 __attribute__((ext_vector_type(8)));
typedef float f32x4 __attribute__((ext_vector_type(4)));

__device__ __forceinline__ unsigned bf16_rn(float x) {
    unsigned u = __builtin_bit_cast(unsigned, x);
    u += 0x7fffu + ((u >> 16) & 1u);
    return u >> 16;
}
__device__ __forceinline__ float bflo(unsigned u) { return __builtin_bit_cast(float, u << 16); }
__device__ __forceinline__ float bfhi(unsigned u) { return __builtin_bit_cast(float, u & 0xffff0000u); }
__device__ __forceinline__ float gelu_f(float x) {
    return 0.5f * x * (1.f + erff(x * 0.70710678118654752f));
}

// W-frag tile offsets (in uint4 units)
#define OFF_Q 0
#define OFF_K (162 * 64)
#define OFF_V (324 * 64)
#define OFF_1 (486 * 64)
#define OFF_2 (810 * 64)

// ---- prep: y=0/1/2 transpose q/k/v to pixel-major bf16; y=3 pack weights --
__global__ __launch_bounds__(256) void prep_kernel(
    const float* __restrict__ q, const float* __restrict__ k,
    const float* __restrict__ v,
    const float* __restrict__ Wq, const float* __restrict__ Wk,
    const float* __restrict__ Wv, const float* __restrict__ W1,
    const float* __restrict__ W2,
    unsigned* __restrict__ xq, unsigned* __restrict__ xk,
    unsigned* __restrict__ xv, uint4* __restrict__ wp)
{
    if (blockIdx.y < 3) {
        const float* src; unsigned* dst; int nimg;
        switch (blockIdx.y) {
            case 0: src = q; dst = xq; nimg = 2; break;
            case 1: src = k; dst = xk; nimg = 4; break;
            default:src = v; dst = xv; nimg = 4; break;
        }
        int idx = blockIdx.x * 256 + threadIdx.x;
        if (idx >= nimg * AREA * 36) return;
        int a = idx & (AREA - 1);
        int rest = idx >> 12;
        int oct = rest % 36;
        int n = rest / 36;
        const float* s = src + ((long)n * 288 + oct * 8) * AREA + a;
        uint4 u;
        u.x = bf16_rn(s[0])        | (bf16_rn(s[AREA])     << 16);
        u.y = bf16_rn(s[2 * AREA]) | (bf16_rn(s[3 * AREA]) << 16);
        u.z = bf16_rn(s[4 * AREA]) | (bf16_rn(s[5 * AREA]) << 16);
        u.w = bf16_rn(s[6 * AREA]) | (bf16_rn(s[7 * AREA]) << 16);
        *(uint4*)(dst + ((long)n * AREA + a) * 144 + oct * 4) = u;
    } else {
        // pack: frag tile (ot,ks): lane holds W[ot*16+(l&15)][ks*32+(l>>4)*8+j]
        int gw = blockIdx.x * 4 + (threadIdx.x >> 6);
        if (gw >= 1134) return;
        int lane = threadIdx.x & 63;
        const float* W; int Cin, KS, local, off;
        if      (gw < 162) { W = Wq; Cin = 288; KS = 9;  local = gw;       off = OFF_Q; }
        else if (gw < 324) { W = Wk; Cin = 288; KS = 9;  local = gw - 162; off = OFF_K; }
        else if (gw < 486) { W = Wv; Cin = 288; KS = 9;  local = gw - 324; off = OFF_V; }
        else if (gw < 810) { W = W1; Cin = 288; KS = 9;  local = gw - 486; off = OFF_1; }
        else               { W = W2; Cin = 576; KS = 18; local = gw - 810; off = OFF_2; }
        int ot = local / KS, ks = local - ot * KS;
        int o = ot * 16 + (lane & 15);
        int c0 = ks * 32 + ((lane >> 4) << 3);
        const float4* wr = (const float4*)(W + (long)o * Cin + c0);
        float4 f0 = wr[0], f1 = wr[1];
        uint4 u;
        u.x = bf16_rn(f0.x) | (bf16_rn(f0.y) << 16);
        u.y = bf16_rn(f0.z) | (bf16_rn(f0.w) << 16);
        u.z = bf16_rn(f1.x) | (bf16_rn(f1.y) << 16);
        u.w = bf16_rn(f1.z) | (bf16_rn(f1.w) << 16);
        wp[(long)off + (long)local * 64 + lane] = u;
    }
}

// ---- fused q/k/v MFMA projection (z selects input image & dest) ---------
// z 0..1: q -> qp (f32 [site][288]); z 2..5: k -> kv_u[..,0:12];
// z 6..9: v -> kv_u[..,12:24]
__global__ __launch_bounds__(256) void proj_qkv(
    const unsigned* __restrict__ xq, const unsigned* __restrict__ xk,
    const unsigned* __restrict__ xv, const uint4* __restrict__ wp,
    const float* __restrict__ bq, const float* __restrict__ bk,
    const float* __restrict__ bv, float* __restrict__ qp,
    unsigned* __restrict__ kv_u)
{
    const int z = blockIdx.z;
    const unsigned* Xt; const uint4* Wp; const float* bias;
    int outmode, voff, n;
    if (z < 2)      { Xt = xq; Wp = wp + OFF_Q; bias = bq; outmode = 1; voff = 0;  n = z; }
    else if (z < 6) { Xt = xk; Wp = wp + OFF_K; bias = bk; outmode = 2; voff = 0;  n = z - 2; }
    else            { Xt = xv; Wp = wp + OFF_V; bias = bv; outmode = 2; voff = 12; n = z - 6; }

    const int tid = threadIdx.x;
    const int lane = tid & 63;
    const int w = tid >> 6;
    const int ot0 = blockIdx.y * 2;
    const int pw = blockIdx.x * 256 + w * 64;
    const int lcol = lane & 15;
    const int lrow = lane >> 4;

    const uint4* xrow[4];
#pragma unroll
    for (int s = 0; s < 4; ++s)
        xrow[s] = (const uint4*)(Xt + ((long)n * AREA + pw + s * 16 + lcol) * 144);
    const uint4* wa0 = Wp + (long)ot0 * 9 * 64 + lane;
    const uint4* wa1 = Wp + (long)(ot0 + 1) * 9 * 64 + lane;

    f32x4 acc[2][4];
#pragma unroll
    for (int m = 0; m < 2; ++m)
#pragma unroll
        for (int s = 0; s < 4; ++s) acc[m][s] = (f32x4){0.f, 0.f, 0.f, 0.f};

    for (int ks = 0; ks < 9; ++ks) {
        uint4 a0 = wa0[(long)ks * 64];
        uint4 a1 = wa1[(long)ks * 64];
        uint4 b[4];
#pragma unroll
        for (int s = 0; s < 4; ++s) b[s] = xrow[s][ks * 4 + lrow];
        short8 A0 = __builtin_bit_cast(short8, a0);
        short8 A1 = __builtin_bit_cast(short8, a1);
#pragma unroll
        for (int s = 0; s < 4; ++s) {
            short8 B = __builtin_bit_cast(short8, b[s]);
            acc[0][s] = __builtin_amdgcn_mfma_f32_16x16x32_bf16(A0, B, acc[0][s], 0, 0, 0);
            acc[1][s] = __builtin_amdgcn_mfma_f32_16x16x32_bf16(A1, B, acc[1][s], 0, 0, 0);
        }
    }

#pragma unroll
    for (int m = 0; m < 2; ++m) {
        const int obase = (ot0 + m) * 16 + lrow * 4;
        const float b0 = bias[obase], b1 = bias[obase + 1];
        const float b2 = bias[obase + 2], b3 = bias[obase + 3];
#pragma unroll
        for (int s = 0; s < 4; ++s) {
            const int pcol = pw + s * 16 + lcol;
            f32x4 a = acc[m][s];
            float v0 = a[0] + b0, v1 = a[1] + b1, v2 = a[2] + b2, v3 = a[3] + b3;
            if (outmode == 1) {
                float4 st = {v0, v1, v2, v3};
                *(float4*)(qp + ((long)n * AREA + pcol) * 288 + obase) = st;
            } else {
                int g = obase / 24, d0 = obase % 24;
                unsigned* ub = kv_u +
                    ((long)(n * 12 + g) * AREA + pcol) * 24 + voff + (d0 >> 1);
                uint2 st;
                st.x = bf16_rn(v0) | (bf16_rn(v1) << 16);
                st.y = bf16_rn(v2) | (bf16_rn(v3) << 16);
                *(uint2*)ub = st;
            }
        }
    }
}

// ---- FFN MFMA projection (template epilogue) ----------------------------
// OUT 0: f32 chan-major + residual (FFN2)   OUT 3: bf16 [site][] + GELU (FFN1)
template<int OUT>
__global__ __launch_bounds__(256) void proj_mfma(
    const unsigned* __restrict__ Xt, const uint4* __restrict__ Wp,
    const float* __restrict__ bias, void* __restrict__ outp,
    const float* __restrict__ res, int KS, int RSu)
{
    const int tid = threadIdx.x;
    const int lane = tid & 63;
    const int w = tid >> 6;
    const int n = blockIdx.z;
    const int ot0 = blockIdx.y * 2;
    const int pw = blockIdx.x * 256 + w * 64;
    const int lcol = lane & 15;
    const int lrow = lane >> 4;

    const uint4* xrow[4];
#pragma unroll
    for (int s = 0; s < 4; ++s)
        xrow[s] = (const uint4*)(Xt + ((long)n * AREA + pw + s * 16 + lcol) * RSu);
    const uint4* wa0 = Wp + (long)ot0 * KS * 64 + lane;
    const uint4* wa1 = Wp + (long)(ot0 + 1) * KS * 64 + lane;

    f32x4 acc[2][4];
#pragma unroll
    for (int m = 0; m < 2; ++m)
#pragma unroll
        for (int s = 0; s < 4; ++s) acc[m][s] = (f32x4){0.f, 0.f, 0.f, 0.f};

    for (int ks = 0; ks < KS; ++ks) {
        uint4 a0 = wa0[(long)ks * 64];
        uint4 a1 = wa1[(long)ks * 64];
        uint4 b[4];
#pragma unroll
        for (int s = 0; s < 4; ++s) b[s] = xrow[s][ks * 4 + lrow];
        short8 A0 = __builtin_bit_cast(short8, a0);
        short8 A1 = __builtin_bit_cast(short8, a1);
#pragma unroll
        for (int s = 0; s < 4; ++s) {
            short8 B = __builtin_bit_cast(short8, b[s]);
            acc[0][s] = __builtin_amdgcn_mfma_f32_16x16x32_bf16(A0, B, acc[0][s], 0, 0, 0);
            acc[1][s] = __builtin_amdgcn_mfma_f32_16x16x32_bf16(A1, B, acc[1][s], 0, 0, 0);
        }
    }

#pragma unroll
    for (int m = 0; m < 2; ++m) {
        const int obase = (ot0 + m) * 16 + lrow * 4;
        const float b0 = bias[obase], b1 = bias[obase + 1];
        const float b2 = bias[obase + 2], b3 = bias[obase + 3];
#pragma unroll
        for (int s = 0; s < 4; ++s) {
            const int pcol = pw + s * 16 + lcol;
            f32x4 a = acc[m][s];
            float v0 = a[0] + b0, v1 = a[1] + b1, v2 = a[2] + b2, v3 = a[3] + b3;
            if (OUT == 3) {
                v0 = gelu_f(v0); v1 = gelu_f(v1); v2 = gelu_f(v2); v3 = gelu_f(v3);
                uint2 st;
                st.x = bf16_rn(v0) | (bf16_rn(v1) << 16);
                st.y = bf16_rn(v2) | (bf16_rn(v3) << 16);
                *(uint2*)((unsigned*)outp + ((long)n * AREA + pcol) * 288 + (obase >> 1)) = st;
            } else {
                float* fb = (float*)outp;
                float vals[4] = {v0, v1, v2, v3};
#pragma unroll
                for (int r = 0; r < 4; ++r) {
                    long addr = ((long)n * 288 + obase + r) * AREA + pcol;
                    fb[addr] = vals[r] + res[addr];
                }
            }
        }
    }
}

// ---------------- deformable attention ---------------------------------
// 4 lanes/site: bit0 = role (K/V), bit1 = clip partition.
// Per-lane 9 samples; clip states merged via shfl_xor(2) at the end.
__global__ __launch_bounds__(256) void deform_attn_kernel(
    const float* __restrict__ qp, const unsigned* __restrict__ kv,
    const float* __restrict__ offs, float* __restrict__ o,
    unsigned* __restrict__ ot)
{
    const int t = blockIdx.x * 256 + threadIdx.x;
    const int role = t & 1;
    const int clip = (t >> 1) & 1;
    const int site = t >> 2;                 // (b*12 + g)*A + a
    const int a = site & (AREA - 1);
    const int g = (site >> 12) % 12;
    const int b = site / (12 * AREA);
    const int py = a >> 6, px = a & 63;
    const float scale = 0.20412414523193150818f;   // 1/sqrt(24)

    float qv[24];
    {
        const float4* qb = (const float4*)(qp + ((long)b * AREA + a) * 288 + g * 24);
#pragma unroll
        for (int i = 0; i < 6; ++i) {
            float4 qq = qb[i];
            qv[4*i+0] = qq.x * scale; qv[4*i+1] = qq.y * scale;
            qv[4*i+2] = qq.z * scale; qv[4*i+3] = qq.w * scale;
        }
    }

    float m = -1e30f, l = 0.f;
    float outv[24];
#pragma unroll
    for (int d = 0; d < 24; ++d) outv[d] = 0.f;

    const unsigned* __restrict__ cb =
        kv + (long)((b * 2 + clip) * 12 + g) * AREA * 24 + role * 12;
    const float* __restrict__ obase =
        offs + ((long)b * 432 + (clip * 12 + g) * 18) * AREA;
#pragma unroll 1
    for (int k = 0; k < 9; ++k) {
        float oy = obase[(long)(2 * k) * AREA + a];
        float ox = obase[(long)(2 * k + 1) * AREA + a];
        int ky = k / 3, kx = k - ky * 3;
        float ys = (float)(py + ky - 1) + oy;
        float xs_ = (float)(px + kx - 1) + ox;
        float y0f = floorf(ys), x0f = floorf(xs_);
        float dy = ys - y0f, dx = xs_ - x0f;
        float wy[2] = {1.f - dy, dy};
        float wx[2] = {1.f - dx, dx};
        long  idx4[4];
        float w4[4];
#pragma unroll
        for (int cy = 0; cy < 2; ++cy) {
            float yc = y0f + (float)cy;
            bool vy = (yc >= 0.f) && (yc <= 63.f);
            int yi = (int)fminf(fmaxf(yc, 0.f), 63.f);
#pragma unroll
            for (int cx = 0; cx < 2; ++cx) {
                float xc = x0f + (float)cx;
                bool vx = (xc >= 0.f) && (xc <= 63.f);
                int xi = (int)fminf(fmaxf(xc, 0.f), 63.f);
                w4[cy * 2 + cx] = wy[cy] * wx[cx] * ((vy && vx) ? 1.f : 0.f);
                idx4[cy * 2 + cx] = (long)(yi * 64 + xi) * 24;
            }
        }
        float xs[24];
#pragma unroll
        for (int j = 0; j < 24; ++j) xs[j] = 0.f;
        float sh = 0.f;
#pragma unroll
        for (int c = 0; c < 4; ++c) {
            const uint4* pc = (const uint4*)(cb + idx4[c]);
            uint4 u0 = pc[0], u1 = pc[1], u2 = pc[2];
            unsigned uu[12] = {u0.x, u0.y, u0.z, u0.w,
                               u1.x, u1.y, u1.z, u1.w,
                               u2.x, u2.y, u2.z, u2.w};
            float w = w4[c];
            float d = 0.f;
#pragma unroll
            for (int j = 0; j < 12; ++j) {
                float lo = bflo(uu[j]), hi = bfhi(uu[j]);
                d = fmaf(qv[2 * j], lo, d);
                d = fmaf(qv[2 * j + 1], hi, d);
                xs[2 * j]     = fmaf(w, lo, xs[2 * j]);
                xs[2 * j + 1] = fmaf(w, hi, xs[2 * j + 1]);
            }
            sh = fmaf(w, d, sh);
        }
        float sx = __shfl_xor(sh, 1);
        float s = role ? sx : sh;          // K-lane's full dot
        float mn = fmaxf(m, s);
        float corr = __expf(m - mn);
        float p = __expf(s - mn);
        l = l * corr + p;
        m = mn;
#pragma unroll
        for (int j = 0; j < 24; ++j)
            outv[j] = fmaf(outv[j], corr, p * xs[j]);
    }

    // ---- merge the two clip partitions (lanes differing in bit 1) ----
    float mo  = __shfl_xor(m, 2);
    float lo2 = __shfl_xor(l, 2);
    float mn = fmaxf(m, mo);
    float fs = __expf(m - mn), fo = __expf(mo - mn);
    float lm = l * fs + lo2 * fo;
    float inv = 1.f / lm;
#pragma unroll
    for (int d = 0; d < 24; ++d) {
        float ovo = __shfl_xor(outv[d], 2);
        outv[d] = (outv[d] * fs + ovo * fo) * inv;
    }

    if (role == 1 && clip == 0) {
        float ov[24];
#pragma unroll
        for (int d = 0; d < 24; ++d) {
            ov[d] = outv[d];
            o[((long)b * 288 + g * 24 + d) * AREA + a] = ov[d];
        }
        unsigned* tb = ot + ((long)b * AREA + a) * 144 + g * 12;
        uint4 s0, s1, s2;
        s0.x = bf16_rn(ov[0])  | (bf16_rn(ov[1])  << 16);
        s0.y = bf16_rn(ov[2])  | (bf16_rn(ov[3])  << 16);
        s0.z = bf16_rn(ov[4])  | (bf16_rn(ov[5])  << 16);
        s0.w = bf16_rn(ov[6])  | (bf16_rn(ov[7])  << 16);
        s1.x = bf16_rn(ov[8])  | (bf16_rn(ov[9])  << 16);
        s1.y = bf16_rn(ov[10]) | (bf16_rn(ov[11]) << 16);
        s1.z = bf16_rn(ov[12]) | (bf16_rn(ov[13]) << 16);
        s1.w = bf16_rn(ov[14]) | (bf16_rn(ov[15]) << 16);
        s2.x = bf16_rn(ov[16]) | (bf16_rn(ov[17]) << 16);
        s2.y = bf16_rn(ov[18]) | (bf16_rn(ov[19]) << 16);
        s2.z = bf16_rn(ov[20]) | (bf16_rn(ov[21]) << 16);
        s2.w = bf16_rn(ov[22]) | (bf16_rn(ov[23]) << 16);
        ((uint4*)tb)[0] = s0; ((uint4*)tb)[1] = s1; ((uint4*)tb)[2] = s2;
    }
}

extern "C" void kernel_launch(void* const* d_in, const int* in_sizes, int n_in,
                              void* d_out, int out_size, void* d_ws, size_t ws_size,
                              hipStream_t stream) {
    const float* q      = (const float*)d_in[0];
    const float* k      = (const float*)d_in[1];
    const float* v      = (const float*)d_in[2];
    const float* offset = (const float*)d_in[3];
    const float* Wq     = (const float*)d_in[4];
    const float* bq     = (const float*)d_in[5];
    const float* Wk     = (const float*)d_in[6];
    const float* bk     = (const float*)d_in[7];
    const float* Wv     = (const float*)d_in[8];
    const float* bv     = (const float*)d_in[9];
    const float* W1     = (const float*)d_in[10];
    const float* b1     = (const float*)d_in[11];
    const float* W2     = (const float*)d_in[12];
    const float* b2     = (const float*)d_in[13];
    float* out = (float*)d_out;
    float* ws  = (float*)d_ws;

    float*    qp   = ws;                               // 2,359,296 f32
    unsigned* kv_u = (unsigned*)(ws + 2359296);        // 4,718,592 u32
    unsigned* xq   = (unsigned*)(ws + 7077888);        // 1,179,648 u32
    unsigned* xk   = (unsigned*)(ws + 8257536);        // 2,359,296 u32 (x1 aliases)
    unsigned* xv   = (unsigned*)(ws + 10616832);       // 2,359,296 u32 (o_t aliases)
    uint4*    wp   = (uint4*)(ws + 12976128);
    unsigned* x1   = xk;
    unsigned* o_t  = xv;

    // 1) transpose inputs + pack weights
    prep_kernel<<<dim3(2304, 4), dim3(256), 0, stream>>>(
        q, k, v, Wq, Wk, Wv, W1, W2, xq, xk, xv, wp);
    // 2) fused q/k/v projections
    proj_qkv<<<dim3(16, 9, 10), dim3(256), 0, stream>>>(
        xq, xk, xv, wp, bq, bk, bv, qp, kv_u);
    // 3) deformable attention -> d_out (f32) + o_t (bf16 pixel-major)
    deform_attn_kernel<<<dim3(1536), dim3(256), 0, stream>>>(
        qp, kv_u, offset, out, o_t);
    // 4) FFN1: o_t(288) -> x1(576) bf16 pixel-major, GELU
    proj_mfma<3><<<dim3(16, 18, 2), dim3(256), 0, stream>>>(
        o_t, wp + OFF_1, b1, x1, nullptr, 9, 144);
    // 5) FFN2: x1(576) -> d_out f32 chan-major + residual o
    proj_mfma<0><<<dim3(16, 9, 2), dim3(256), 0, stream>>>(
        x1, wp + OFF_2, b2, out, out, 18, 288);
}

// Round 8
// 133.995 us; speedup vs baseline: 1.1660x; 1.1660x over previous
//
#include <hip/hip_runtime.h>

#define AREA 4096

typedef short short8 __attribute__((ext_vector_type(8)));
typedef float f32x4 __attribute__((ext_vector_type(4)));

__device__ __forceinline__ unsigned bf16_rn(float x) {
    unsigned u = __builtin_bit_cast(unsigned, x);
    u += 0x7fffu + ((u >> 16) & 1u);
    return u >> 16;
}
__device__ __forceinline__ float bflo(unsigned u) { return __builtin_bit_cast(float, u << 16); }
__device__ __forceinline__ float bfhi(unsigned u) { return __builtin_bit_cast(float, u & 0xffff0000u); }
__device__ __forceinline__ float gelu_f(float x) {
    return 0.5f * x * (1.f + erff(x * 0.70710678118654752f));
}

// W-frag tile offsets (in uint4 units)
#define OFF_Q 0
#define OFF_K (162 * 64)
#define OFF_V (324 * 64)
#define OFF_1 (486 * 64)
#define OFF_2 (810 * 64)

// ---- prep: y=0/1/2 transpose q/k/v to pixel-major bf16; y=3 pack weights --
__global__ __launch_bounds__(256) void prep_kernel(
    const float* __restrict__ q, const float* __restrict__ k,
    const float* __restrict__ v,
    const float* __restrict__ Wq, const float* __restrict__ Wk,
    const float* __restrict__ Wv, const float* __restrict__ W1,
    const float* __restrict__ W2,
    unsigned* __restrict__ xq, unsigned* __restrict__ xk,
    unsigned* __restrict__ xv, uint4* __restrict__ wp)
{
    if (blockIdx.y < 3) {
        const float* src; unsigned* dst; int nimg;
        switch (blockIdx.y) {
            case 0: src = q; dst = xq; nimg = 2; break;
            case 1: src = k; dst = xk; nimg = 4; break;
            default:src = v; dst = xv; nimg = 4; break;
        }
        int idx = blockIdx.x * 256 + threadIdx.x;
        if (idx >= nimg * AREA * 36) return;
        int a = idx & (AREA - 1);
        int rest = idx >> 12;
        int oct = rest % 36;
        int n = rest / 36;
        const float* s = src + ((long)n * 288 + oct * 8) * AREA + a;
        uint4 u;
        u.x = bf16_rn(s[0])        | (bf16_rn(s[AREA])     << 16);
        u.y = bf16_rn(s[2 * AREA]) | (bf16_rn(s[3 * AREA]) << 16);
        u.z = bf16_rn(s[4 * AREA]) | (bf16_rn(s[5 * AREA]) << 16);
        u.w = bf16_rn(s[6 * AREA]) | (bf16_rn(s[7 * AREA]) << 16);
        *(uint4*)(dst + ((long)n * AREA + a) * 144 + oct * 4) = u;
    } else {
        // pack: frag tile (ot,ks): lane holds W[ot*16+(l&15)][ks*32+(l>>4)*8+j]
        int gw = blockIdx.x * 4 + (threadIdx.x >> 6);
        if (gw >= 1134) return;
        int lane = threadIdx.x & 63;
        const float* W; int Cin, KS, local, off;
        if      (gw < 162) { W = Wq; Cin = 288; KS = 9;  local = gw;       off = OFF_Q; }
        else if (gw < 324) { W = Wk; Cin = 288; KS = 9;  local = gw - 162; off = OFF_K; }
        else if (gw < 486) { W = Wv; Cin = 288; KS = 9;  local = gw - 324; off = OFF_V; }
        else if (gw < 810) { W = W1; Cin = 288; KS = 9;  local = gw - 486; off = OFF_1; }
        else               { W = W2; Cin = 576; KS = 18; local = gw - 810; off = OFF_2; }
        int ot = local / KS, ks = local - ot * KS;
        int o = ot * 16 + (lane & 15);
        int c0 = ks * 32 + ((lane >> 4) << 3);
        const float4* wr = (const float4*)(W + (long)o * Cin + c0);
        float4 f0 = wr[0], f1 = wr[1];
        uint4 u;
        u.x = bf16_rn(f0.x) | (bf16_rn(f0.y) << 16);
        u.y = bf16_rn(f0.z) | (bf16_rn(f0.w) << 16);
        u.z = bf16_rn(f1.x) | (bf16_rn(f1.y) << 16);
        u.w = bf16_rn(f1.z) | (bf16_rn(f1.w) << 16);
        wp[(long)off + (long)local * 64 + lane] = u;
    }
}

// ---- fused q/k/v MFMA projection (z selects input image & dest) ---------
// z 0..1: q -> qp_u (bf16 [site][144 u32]); z 2..5: k -> kv_u[..,0:12];
// z 6..9: v -> kv_u[..,12:24]
__global__ __launch_bounds__(256) void proj_qkv(
    const unsigned* __restrict__ xq, const unsigned* __restrict__ xk,
    const unsigned* __restrict__ xv, const uint4* __restrict__ wp,
    const float* __restrict__ bq, const float* __restrict__ bk,
    const float* __restrict__ bv, unsigned* __restrict__ qp_u,
    unsigned* __restrict__ kv_u)
{
    const int z = blockIdx.z;
    const unsigned* Xt; const uint4* Wp; const float* bias;
    int outmode, voff, n;
    if (z < 2)      { Xt = xq; Wp = wp + OFF_Q; bias = bq; outmode = 1; voff = 0;  n = z; }
    else if (z < 6) { Xt = xk; Wp = wp + OFF_K; bias = bk; outmode = 2; voff = 0;  n = z - 2; }
    else            { Xt = xv; Wp = wp + OFF_V; bias = bv; outmode = 2; voff = 12; n = z - 6; }

    const int tid = threadIdx.x;
    const int lane = tid & 63;
    const int w = tid >> 6;
    const int ot0 = blockIdx.y * 2;
    const int pw = blockIdx.x * 256 + w * 64;
    const int lcol = lane & 15;
    const int lrow = lane >> 4;

    const uint4* xrow[4];
#pragma unroll
    for (int s = 0; s < 4; ++s)
        xrow[s] = (const uint4*)(Xt + ((long)n * AREA + pw + s * 16 + lcol) * 144);
    const uint4* wa0 = Wp + (long)ot0 * 9 * 64 + lane;
    const uint4* wa1 = Wp + (long)(ot0 + 1) * 9 * 64 + lane;

    f32x4 acc[2][4];
#pragma unroll
    for (int m = 0; m < 2; ++m)
#pragma unroll
        for (int s = 0; s < 4; ++s) acc[m][s] = (f32x4){0.f, 0.f, 0.f, 0.f};

    for (int ks = 0; ks < 9; ++ks) {
        uint4 a0 = wa0[(long)ks * 64];
        uint4 a1 = wa1[(long)ks * 64];
        uint4 b[4];
#pragma unroll
        for (int s = 0; s < 4; ++s) b[s] = xrow[s][ks * 4 + lrow];
        short8 A0 = __builtin_bit_cast(short8, a0);
        short8 A1 = __builtin_bit_cast(short8, a1);
#pragma unroll
        for (int s = 0; s < 4; ++s) {
            short8 B = __builtin_bit_cast(short8, b[s]);
            acc[0][s] = __builtin_amdgcn_mfma_f32_16x16x32_bf16(A0, B, acc[0][s], 0, 0, 0);
            acc[1][s] = __builtin_amdgcn_mfma_f32_16x16x32_bf16(A1, B, acc[1][s], 0, 0, 0);
        }
    }

#pragma unroll
    for (int m = 0; m < 2; ++m) {
        const int obase = (ot0 + m) * 16 + lrow * 4;
        const float b0 = bias[obase], b1 = bias[obase + 1];
        const float b2 = bias[obase + 2], b3 = bias[obase + 3];
#pragma unroll
        for (int s = 0; s < 4; ++s) {
            const int pcol = pw + s * 16 + lcol;
            f32x4 a = acc[m][s];
            float v0 = a[0] + b0, v1 = a[1] + b1, v2 = a[2] + b2, v3 = a[3] + b3;
            uint2 st;
            st.x = bf16_rn(v0) | (bf16_rn(v1) << 16);
            st.y = bf16_rn(v2) | (bf16_rn(v3) << 16);
            if (outmode == 1) {
                *(uint2*)(qp_u + ((long)n * AREA + pcol) * 144 + (obase >> 1)) = st;
            } else {
                int g = obase / 24, d0 = obase % 24;
                unsigned* ub = kv_u +
                    ((long)(n * 12 + g) * AREA + pcol) * 24 + voff + (d0 >> 1);
                *(uint2*)ub = st;
            }
        }
    }
}

// ---- FFN MFMA projection (template epilogue) ----------------------------
// OUT 0: f32 chan-major + residual (FFN2)   OUT 3: bf16 [site][] + GELU (FFN1)
template<int OUT>
__global__ __launch_bounds__(256) void proj_mfma(
    const unsigned* __restrict__ Xt, const uint4* __restrict__ Wp,
    const float* __restrict__ bias, void* __restrict__ outp,
    const float* __restrict__ res, int KS, int RSu)
{
    const int tid = threadIdx.x;
    const int lane = tid & 63;
    const int w = tid >> 6;
    const int n = blockIdx.z;
    const int ot0 = blockIdx.y * 2;
    const int pw = blockIdx.x * 256 + w * 64;
    const int lcol = lane & 15;
    const int lrow = lane >> 4;

    const uint4* xrow[4];
#pragma unroll
    for (int s = 0; s < 4; ++s)
        xrow[s] = (const uint4*)(Xt + ((long)n * AREA + pw + s * 16 + lcol) * RSu);
    const uint4* wa0 = Wp + (long)ot0 * KS * 64 + lane;
    const uint4* wa1 = Wp + (long)(ot0 + 1) * KS * 64 + lane;

    f32x4 acc[2][4];
#pragma unroll
    for (int m = 0; m < 2; ++m)
#pragma unroll
        for (int s = 0; s < 4; ++s) acc[m][s] = (f32x4){0.f, 0.f, 0.f, 0.f};

    for (int ks = 0; ks < KS; ++ks) {
        uint4 a0 = wa0[(long)ks * 64];
        uint4 a1 = wa1[(long)ks * 64];
        uint4 b[4];
#pragma unroll
        for (int s = 0; s < 4; ++s) b[s] = xrow[s][ks * 4 + lrow];
        short8 A0 = __builtin_bit_cast(short8, a0);
        short8 A1 = __builtin_bit_cast(short8, a1);
#pragma unroll
        for (int s = 0; s < 4; ++s) {
            short8 B = __builtin_bit_cast(short8, b[s]);
            acc[0][s] = __builtin_amdgcn_mfma_f32_16x16x32_bf16(A0, B, acc[0][s], 0, 0, 0);
            acc[1][s] = __builtin_amdgcn_mfma_f32_16x16x32_bf16(A1, B, acc[1][s], 0, 0, 0);
        }
    }

#pragma unroll
    for (int m = 0; m < 2; ++m) {
        const int obase = (ot0 + m) * 16 + lrow * 4;
        const float b0 = bias[obase], b1 = bias[obase + 1];
        const float b2 = bias[obase + 2], b3 = bias[obase + 3];
#pragma unroll
        for (int s = 0; s < 4; ++s) {
            const int pcol = pw + s * 16 + lcol;
            f32x4 a = acc[m][s];
            float v0 = a[0] + b0, v1 = a[1] + b1, v2 = a[2] + b2, v3 = a[3] + b3;
            if (OUT == 3) {
                v0 = gelu_f(v0); v1 = gelu_f(v1); v2 = gelu_f(v2); v3 = gelu_f(v3);
                uint2 st;
                st.x = bf16_rn(v0) | (bf16_rn(v1) << 16);
                st.y = bf16_rn(v2) | (bf16_rn(v3) << 16);
                *(uint2*)((unsigned*)outp + ((long)n * AREA + pcol) * 288 + (obase >> 1)) = st;
            } else {
                float* fb = (float*)outp;
                float vals[4] = {v0, v1, v2, v3};
#pragma unroll
                for (int r = 0; r < 4; ++r) {
                    long addr = ((long)n * 288 + obase + r) * AREA + pcol;
                    fb[addr] = vals[r] + res[addr];
                }
            }
        }
    }
}

// ---------------- deformable attention ---------------------------------
// 4 lanes/site: bit0 = role (K/V), bit1 = clip partition.
// XCD-aware swizzle: 1536 blocks -> XCD x gets logical blocks [x*192,(x+1)*192)
// so each XCD's concurrent gather footprint is ~6 contiguous slabs (~2.4MB < L2).
__global__ __launch_bounds__(256) void deform_attn_kernel(
    const unsigned* __restrict__ qp, const unsigned* __restrict__ kv,
    const float* __restrict__ offs, float* __restrict__ o,
    unsigned* __restrict__ ot)
{
    const int bid = blockIdx.x;
    const int swz = (bid & 7) * 192 + (bid >> 3);    // 1536 = 8 * 192, bijective
    const int t = swz * 256 + threadIdx.x;
    const int role = t & 1;
    const int clip = (t >> 1) & 1;
    const int site = t >> 2;                 // (b*12 + g)*A + a
    const int a = site & (AREA - 1);
    const int g = (site >> 12) % 12;
    const int b = site / (12 * AREA);
    const int py = a >> 6, px = a & 63;
    const float scale = 0.20412414523193150818f;   // 1/sqrt(24)

    float qv[24];
    {
        const uint4* qb = (const uint4*)(qp + ((long)b * AREA + a) * 144 + g * 12);
        uint4 q0 = qb[0], q1 = qb[1], q2 = qb[2];
        unsigned uq[12] = {q0.x, q0.y, q0.z, q0.w, q1.x, q1.y, q1.z, q1.w,
                           q2.x, q2.y, q2.z, q2.w};
#pragma unroll
        for (int j = 0; j < 12; ++j) {
            qv[2 * j]     = bflo(uq[j]) * scale;
            qv[2 * j + 1] = bfhi(uq[j]) * scale;
        }
    }

    float m = -1e30f, l = 0.f;
    float outv[24];
#pragma unroll
    for (int d = 0; d < 24; ++d) outv[d] = 0.f;

    const unsigned* __restrict__ cb =
        kv + (long)((b * 2 + clip) * 12 + g) * AREA * 24 + role * 12;
    const float* __restrict__ obase =
        offs + ((long)b * 432 + (clip * 12 + g) * 18) * AREA;
#pragma unroll 1
    for (int k = 0; k < 9; ++k) {
        float oy = obase[(long)(2 * k) * AREA + a];
        float ox = obase[(long)(2 * k + 1) * AREA + a];
        int ky = k / 3, kx = k - ky * 3;
        float ys = (float)(py + ky - 1) + oy;
        float xs_ = (float)(px + kx - 1) + ox;
        float y0f = floorf(ys), x0f = floorf(xs_);
        float dy = ys - y0f, dx = xs_ - x0f;
        float wy[2] = {1.f - dy, dy};
        float wx[2] = {1.f - dx, dx};
        long  idx4[4];
        float w4[4];
#pragma unroll
        for (int cy = 0; cy < 2; ++cy) {
            float yc = y0f + (float)cy;
            bool vy = (yc >= 0.f) && (yc <= 63.f);
            int yi = (int)fminf(fmaxf(yc, 0.f), 63.f);
#pragma unroll
            for (int cx = 0; cx < 2; ++cx) {
                float xc = x0f + (float)cx;
                bool vx = (xc >= 0.f) && (xc <= 63.f);
                int xi = (int)fminf(fmaxf(xc, 0.f), 63.f);
                w4[cy * 2 + cx] = wy[cy] * wx[cx] * ((vy && vx) ? 1.f : 0.f);
                idx4[cy * 2 + cx] = (long)(yi * 64 + xi) * 24;
            }
        }
        float xs[24];
#pragma unroll
        for (int j = 0; j < 24; ++j) xs[j] = 0.f;
        float sh = 0.f;
#pragma unroll
        for (int c = 0; c < 4; ++c) {
            const uint4* pc = (const uint4*)(cb + idx4[c]);
            uint4 u0 = pc[0], u1 = pc[1], u2 = pc[2];
            unsigned uu[12] = {u0.x, u0.y, u0.z, u0.w,
                               u1.x, u1.y, u1.z, u1.w,
                               u2.x, u2.y, u2.z, u2.w};
            float w = w4[c];
            float d = 0.f;
#pragma unroll
            for (int j = 0; j < 12; ++j) {
                float lo = bflo(uu[j]), hi = bfhi(uu[j]);
                d = fmaf(qv[2 * j], lo, d);
                d = fmaf(qv[2 * j + 1], hi, d);
                xs[2 * j]     = fmaf(w, lo, xs[2 * j]);
                xs[2 * j + 1] = fmaf(w, hi, xs[2 * j + 1]);
            }
            sh = fmaf(w, d, sh);
        }
        float sx = __shfl_xor(sh, 1);
        float s = role ? sx : sh;          // K-lane's full dot
        float mn = fmaxf(m, s);
        float corr = __expf(m - mn);
        float p = __expf(s - mn);
        l = l * corr + p;
        m = mn;
#pragma unroll
        for (int j = 0; j < 24; ++j)
            outv[j] = fmaf(outv[j], corr, p * xs[j]);
    }

    // ---- merge the two clip partitions (lanes differing in bit 1) ----
    float mo  = __shfl_xor(m, 2);
    float lo2 = __shfl_xor(l, 2);
    float mn = fmaxf(m, mo);
    float fs = __expf(m - mn), fo = __expf(mo - mn);
    float lm = l * fs + lo2 * fo;
    float inv = 1.f / lm;
#pragma unroll
    for (int d = 0; d < 24; ++d) {
        float ovo = __shfl_xor(outv[d], 2);
        outv[d] = (outv[d] * fs + ovo * fo) * inv;
    }

    if (role == 1 && clip == 0) {
        float ov[24];
#pragma unroll
        for (int d = 0; d < 24; ++d) {
            ov[d] = outv[d];
            o[((long)b * 288 + g * 24 + d) * AREA + a] = ov[d];
        }
        unsigned* tb = ot + ((long)b * AREA + a) * 144 + g * 12;
        uint4 s0, s1, s2;
        s0.x = bf16_rn(ov[0])  | (bf16_rn(ov[1])  << 16);
        s0.y = bf16_rn(ov[2])  | (bf16_rn(ov[3])  << 16);
        s0.z = bf16_rn(ov[4])  | (bf16_rn(ov[5])  << 16);
        s0.w = bf16_rn(ov[6])  | (bf16_rn(ov[7])  << 16);
        s1.x = bf16_rn(ov[8])  | (bf16_rn(ov[9])  << 16);
        s1.y = bf16_rn(ov[10]) | (bf16_rn(ov[11]) << 16);
        s1.z = bf16_rn(ov[12]) | (bf16_rn(ov[13]) << 16);
        s1.w = bf16_rn(ov[14]) | (bf16_rn(ov[15]) << 16);
        s2.x = bf16_rn(ov[16]) | (bf16_rn(ov[17]) << 16);
        s2.y = bf16_rn(ov[18]) | (bf16_rn(ov[19]) << 16);
        s2.z = bf16_rn(ov[20]) | (bf16_rn(ov[21]) << 16);
        s2.w = bf16_rn(ov[22]) | (bf16_rn(ov[23]) << 16);
        ((uint4*)tb)[0] = s0; ((uint4*)tb)[1] = s1; ((uint4*)tb)[2] = s2;
    }
}

extern "C" void kernel_launch(void* const* d_in, const int* in_sizes, int n_in,
                              void* d_out, int out_size, void* d_ws, size_t ws_size,
                              hipStream_t stream) {
    const float* q      = (const float*)d_in[0];
    const float* k      = (const float*)d_in[1];
    const float* v      = (const float*)d_in[2];
    const float* offset = (const float*)d_in[3];
    const float* Wq     = (const float*)d_in[4];
    const float* bq     = (const float*)d_in[5];
    const float* Wk     = (const float*)d_in[6];
    const float* bk     = (const float*)d_in[7];
    const float* Wv     = (const float*)d_in[8];
    const float* bv     = (const float*)d_in[9];
    const float* W1     = (const float*)d_in[10];
    const float* b1     = (const float*)d_in[11];
    const float* W2     = (const float*)d_in[12];
    const float* b2     = (const float*)d_in[13];
    float* out = (float*)d_out;
    float* ws  = (float*)d_ws;

    unsigned* qp_u = (unsigned*)ws;                    // 1,179,648 u32
    unsigned* kv_u = (unsigned*)(ws + 2359296);        // 4,718,592 u32
    unsigned* xq   = (unsigned*)(ws + 7077888);        // 1,179,648 u32
    unsigned* xk   = (unsigned*)(ws + 8257536);        // 2,359,296 u32 (x1 aliases)
    unsigned* xv   = (unsigned*)(ws + 10616832);       // 2,359,296 u32 (o_t aliases)
    uint4*    wp   = (uint4*)(ws + 12976128);
    unsigned* x1   = xk;
    unsigned* o_t  = xv;

    // 1) transpose inputs + pack weights
    prep_kernel<<<dim3(2304, 4), dim3(256), 0, stream>>>(
        q, k, v, Wq, Wk, Wv, W1, W2, xq, xk, xv, wp);
    // 2) fused q/k/v projections
    proj_qkv<<<dim3(16, 9, 10), dim3(256), 0, stream>>>(
        xq, xk, xv, wp, bq, bk, bv, qp_u, kv_u);
    // 3) deformable attention -> d_out (f32) + o_t (bf16 pixel-major)
    deform_attn_kernel<<<dim3(1536), dim3(256), 0, stream>>>(
        qp_u, kv_u, offset, out, o_t);
    // 4) FFN1: o_t(288) -> x1(576) bf16 pixel-major, GELU
    proj_mfma<3><<<dim3(16, 18, 2), dim3(256), 0, stream>>>(
        o_t, wp + OFF_1, b1, x1, nullptr, 9, 144);
    // 5) FFN2: x1(576) -> d_out f32 chan-major + residual o
    proj_mfma<0><<<dim3(16, 9, 2), dim3(256), 0, stream>>>(
        x1, wp + OFF_2, b2, out, out, 18, 288);
}